// Round 6
// baseline (58.130 us; speedup 1.0000x reference)
//
#include <hip/hip_runtime.h>
#include <hip/hip_bf16.h>

#define DEVINL __device__ __forceinline__

using bf16 = __hip_bfloat16;
typedef __attribute__((ext_vector_type(8))) short short8v;
typedef __attribute__((ext_vector_type(4))) float float4v;

// ===========================================================================
// K1: per-sample graph encoder, 3 levels FUSED into one d-loop.
// 8 waves/block, 1 sample/wave. Writes final[sample][384] to ws as bf16.
// Also converts Wp -> bf16 into ws (first 12288 global threads).
//
// Algebra (validated rounds 2-5): PHYS = complete graph per subset =>
// H_u = msum - m_u; edge MLP msg = relu(a_j + c_k), a_j = (We1-We2)·feat_j+be,
// c_k = We2·feat_k; feat==0 off-subset => cross-level c==0, other-side a==be;
// OTH adjacent other-side joints share Zoth = max_k relu(be + c_k).
// Subsets are disjoint => 13 distinct joints, one fused GEMV pass.
// NOTE (round 5 lesson): NO packed fp32 — CDNA4 fp32 VALU is scalar-rate.
// ===========================================================================

template <int BASE, int CNT, int OTH>
DEVINL float zsum_level(const float (&a_)[13], const float (&c_)[13], float bet) {
    float zs = 0.f;
#pragma unroll
    for (int j = 0; j < CNT; ++j) {
        float z = fmaxf(a_[BASE + j], 0.f);  // cross-level neighbors: c = 0
#pragma unroll
        for (int k = 0; k < CNT; ++k) {
            if (k != j) z = fmaxf(z, a_[BASE + j] + c_[BASE + k]);
        }
        zs += z;
    }
    float zo = 0.f;  // init 0 == folded relu
#pragma unroll
    for (int k = 0; k < CNT; ++k) zo = fmaxf(zo, bet + c_[BASE + k]);
    return zs + (float)OTH * zo;
}

__global__ __launch_bounds__(512, 4) void graph_kernel(
    const float* __restrict__ kp, const float* __restrict__ sc,
    const float* __restrict__ W0, const float* __restrict__ b0,
    const float* __restrict__ W1, const float* __restrict__ b1,
    const float* __restrict__ W2, const float* __restrict__ b2,
    const float* __restrict__ We, const float* __restrict__ be,
    const float* __restrict__ Wp, unsigned short* __restrict__ wpB,
    bf16* __restrict__ fout) {
    __shared__ float2 WW[64][64];        // [d][t^d] = {We1-We2, We2}
    __shared__ float beS[64];
    __shared__ float Praw[8][17][3];
    __shared__ float featAll[8][64][16]; // [wave][d][joint 0..12, pad 16]

    int tid = threadIdx.x;
    int w = tid >> 6;
    int lane = tid & 63;
    int sample = blockIdx.x * 8 + w;

    // ---- Wp -> bf16 conversion (first 12288 global threads, 1 float4 each)
    int gid = blockIdx.x * 512 + tid;
    if (gid < 12288) {
        float4 v = ((const float4*)Wp)[gid];
        union { unsigned short u[4]; uint2 d2; } pk;
        pk.u[0] = __bfloat16_as_ushort(__float2bfloat16(v.x));
        pk.u[1] = __bfloat16_as_ushort(__float2bfloat16(v.y));
        pk.u[2] = __bfloat16_as_ushort(__float2bfloat16(v.z));
        pk.u[3] = __bfloat16_as_ushort(__float2bfloat16(v.w));
        *(uint2*)&wpB[gid * 4] = pk.d2;
    }

    // ---- stage WW (XOR-swizzled column, validated r3) ----
    for (int i = tid; i < 4096; i += 512) {
        int t = i >> 6, d = i & 63;
        float wA = We[t * 128 + d];
        float wB = We[t * 128 + 64 + d];
        WW[d][t ^ d] = make_float2(wA - wB, wB);
    }
    if (tid < 64) beS[tid] = be[tid];

    if (lane < 17) {
        size_t base = (size_t)sample * 17 + lane;
        float2 xy = *(const float2*)(kp + base * 2);
        Praw[w][lane][0] = xy.x;
        Praw[w][lane][1] = xy.y;
        Praw[w][lane][2] = sc[base];
    }
    __syncthreads();

    // ---- min/max via 32-wide shuffle butterfly (validated r3) ----
    int j5 = lane & 31;
    float xx = 0.f, yy = 0.f;
    if (j5 < 17) { xx = Praw[w][j5][0]; yy = Praw[w][j5][1]; }
    float mnx = (j5 < 17) ? xx : 1e30f, mxx = (j5 < 17) ? xx : -1e30f;
    float mny = (j5 < 17) ? yy : 1e30f, mxy = (j5 < 17) ? yy : -1e30f;
#pragma unroll
    for (int off = 16; off; off >>= 1) {
        mnx = fminf(mnx, __shfl_xor(mnx, off, 32));
        mxx = fmaxf(mxx, __shfl_xor(mxx, off, 32));
        mny = fminf(mny, __shfl_xor(mny, off, 32));
        mxy = fmaxf(mxy, __shfl_xor(mxy, off, 32));
    }
    float ix = 1.f / (mxx - mnx + 1e-6f);
    float iy = 1.f / (mxy - mny + 1e-6f);

    // ---- phase 1: lane = input channel d; compute feat for all 13 joints --
    constexpr int JL[13]  = {0, 5, 6, 11, 12, 7, 8, 13, 14, 9, 10, 15, 16};
    constexpr int LEV[13] = {0, 0, 0, 0,  0,  1, 1, 1,  1,  2, 2,  2,  2};

    const float* Wls[3] = {W0, W1, W2};
    const float* bls[3] = {b0, b1, b2};
    float wx[3], wy[3], wsc[3], wb[3];
#pragma unroll
    for (int L = 0; L < 3; ++L) {
        wx[L] = Wls[L][lane * 3 + 0];
        wy[L] = Wls[L][lane * 3 + 1];
        wsc[L] = Wls[L][lane * 3 + 2];
        wb[L] = bls[L][lane];
    }

    float mj[13], sj[13];
    float msum[3] = {0.f, 0.f, 0.f};
#pragma unroll
    for (int jj = 0; jj < 13; ++jj) {
        int j = JL[jj];
        int L = LEV[jj];
        float px = (Praw[w][j][0] - mnx) * ix;
        float py = (Praw[w][j][1] - mny) * iy;
        float ps = Praw[w][j][2];
        float h = fmaxf(px * wx[L] + py * wy[L] + ps * wsc[L] + wb[L], 0.f);
        float m = h * ps;
        mj[jj] = m;
        sj[jj] = ps;
        msum[L] += m;
    }
    float f[16];
#pragma unroll
    for (int jj = 0; jj < 13; ++jj) f[jj] = (msum[LEV[jj]] - mj[jj]) * sj[jj];
    f[13] = f[14] = f[15] = 0.f;
#pragma unroll
    for (int k = 0; k < 4; ++k) {
        *(float4*)&featAll[w][lane][k * 4] =
            make_float4(f[k * 4], f[k * 4 + 1], f[k * 4 + 2], f[k * 4 + 3]);
    }

    // H outputs (per input-channel lane): Hsum_L = (CNT_L - 1) * msum_L
    bf16* outv = fout + (size_t)sample * 384;
    outv[0 * 128 + lane] = __float2bfloat16(4.f * msum[0] * (1.f / 17.f));
    outv[1 * 128 + lane] = __float2bfloat16(3.f * msum[1] * (1.f / 17.f));
    outv[2 * 128 + lane] = __float2bfloat16(3.f * msum[2] * (1.f / 17.f));
    __syncthreads();

    // ---- phase 2: lane = output channel t; ONE fused d-loop, 26 accs ----
    float bet = beS[lane];
    float a_[13], c_[13];
#pragma unroll
    for (int jj = 0; jj < 13; ++jj) { a_[jj] = bet; c_[jj] = 0.f; }

#pragma unroll 4
    for (int d = 0; d < 64; ++d) {
        float2 wv = WW[d][lane ^ d];
        const float* fr = &featAll[w][d][0];
        float4 q0 = *(const float4*)(fr);
        float4 q1 = *(const float4*)(fr + 4);
        float4 q2 = *(const float4*)(fr + 8);
        float f12 = fr[12];
        float ff[13] = {q0.x, q0.y, q0.z, q0.w, q1.x, q1.y, q1.z, q1.w,
                        q2.x, q2.y, q2.z, q2.w, f12};
#pragma unroll
        for (int jj = 0; jj < 13; ++jj) {
            a_[jj] = fmaf(wv.x, ff[jj], a_[jj]);
            c_[jj] = fmaf(wv.y, ff[jj], c_[jj]);
        }
    }

    float z0 = zsum_level<0, 5, 4>(a_, c_, bet);
    float z1 = zsum_level<5, 4, 9>(a_, c_, bet);
    float z2 = zsum_level<9, 4, 4>(a_, c_, bet);
    outv[0 * 128 + 64 + lane] = __float2bfloat16(z0 * (1.f / 17.f));
    outv[1 * 128 + 64 + lane] = __float2bfloat16(z1 * (1.f / 17.f));
    outv[2 * 128 + 64 + lane] = __float2bfloat16(z2 * (1.f / 17.f));
}

// ===========================================================================
// K2: out[8192][128] = fin(bf16)[8192][384] @ WpB^T + bp via MFMA 16x16x32.
// NO LDS, NO barriers. 512 blocks x 8 waves; block = 16-sample m-tile;
// wave w = n-tile w. Bias folded into MFMA C-in. 4096 waves for latency
// hiding. Layouts (m89-verified): A/B row/col = l&15, k = (l>>4)*8+j;
// C: row = (l>>4)*4+reg, col = l&15.
// ===========================================================================
__global__ __launch_bounds__(512) void out_mfma_kernel(
    const bf16* __restrict__ fin, const unsigned short* __restrict__ wpB,
    const float* __restrict__ bp, float* __restrict__ out) {
    int tid = threadIdx.x;
    int w = tid >> 6;
    int lane = tid & 63;
    int m0 = blockIdx.x * 16;
    int r16 = lane & 15;
    int kg = (lane >> 4) * 8;

    const short8v* aptr = (const short8v*)(fin + (size_t)(m0 + r16) * 384 + kg);
    const short8v* bptr = (const short8v*)(wpB + (size_t)(w * 16 + r16) * 384 + kg);

    float bv = bp[w * 16 + r16];
    float4v acc = (float4v){bv, bv, bv, bv};
#pragma unroll
    for (int kt = 0; kt < 12; ++kt) {
        short8v a = aptr[kt * 4];  // +32 elems per kt
        short8v b = bptr[kt * 4];
        acc = __builtin_amdgcn_mfma_f32_16x16x32_bf16(a, b, acc, 0, 0, 0);
    }

    int orow = m0 + (lane >> 4) * 4;
#pragma unroll
    for (int r = 0; r < 4; ++r) {
        out[(size_t)(orow + r) * 128 + w * 16 + r16] = acc[r];
    }
}

// ===========================================================================
// Fallback: validated round-2 fused kernel (used only if ws too small).
// ===========================================================================
template <int LI, int CNT, int OTH>
DEVINL void do_level_f(int w, int lane,
                       const float* __restrict__ Wl, const float* __restrict__ bl,
                       float mnx, float ix, float mny, float iy,
                       const float (*Praw)[17][3],
                       float (*featS)[64][8],
                       const float2 (*WW)[64],
                       const float* beS,
                       float (*finS)[384]) {
    constexpr int SUBJ[3][5] = {{0, 5, 6, 11, 12}, {7, 8, 13, 14, 16}, {9, 10, 15, 16, 16}};
    float w0 = Wl[lane * 3 + 0], w1 = Wl[lane * 3 + 1], w2 = Wl[lane * 3 + 2], bb = bl[lane];
    float mj[CNT], sj[CNT];
    float msum = 0.f;
#pragma unroll
    for (int jj = 0; jj < CNT; ++jj) {
        int j = SUBJ[LI][jj];
        float px = (Praw[w][j][0] - mnx) * ix;
        float py = (Praw[w][j][1] - mny) * iy;
        float ps = Praw[w][j][2];
        float h = fmaxf(px * w0 + py * w1 + ps * w2 + bb, 0.f);
        float m = h * ps;
        mj[jj] = m; sj[jj] = ps; msum += m;
    }
#pragma unroll
    for (int jj = 0; jj < CNT; ++jj) featS[w][lane][jj] = (msum - mj[jj]) * sj[jj];
    float Hsum = (float)(CNT - 1) * msum;
    __syncthreads();
    float a_[CNT], c_[CNT];
    float bet = beS[lane];
#pragma unroll
    for (int jj = 0; jj < CNT; ++jj) { a_[jj] = bet; c_[jj] = 0.f; }
#pragma unroll 4
    for (int d = 0; d < 64; ++d) {
        float2 wv = WW[d][lane];
        const float* fr = &featS[w][d][0];
        float4 f4 = *(const float4*)fr;
        float f[5];
        f[0] = f4.x; f[1] = f4.y; f[2] = f4.z; f[3] = f4.w; f[4] = 0.f;
        if constexpr (CNT > 4) f[4] = fr[4];
#pragma unroll
        for (int jj = 0; jj < CNT; ++jj) {
            a_[jj] = fmaf(wv.x, f[jj], a_[jj]);
            c_[jj] = fmaf(wv.y, f[jj], c_[jj]);
        }
    }
    __syncthreads();
    float zsum = 0.f;
#pragma unroll
    for (int jj = 0; jj < CNT; ++jj) {
        float z = fmaxf(a_[jj], 0.f);
#pragma unroll
        for (int kk = 0; kk < CNT; ++kk)
            if (kk != jj) z = fmaxf(z, a_[jj] + c_[kk]);
        zsum += z;
    }
    float zo = 0.f;
#pragma unroll
    for (int kk = 0; kk < CNT; ++kk) zo = fmaxf(zo, bet + c_[kk]);
    zsum += (float)OTH * zo;
    finS[w][LI * 128 + lane] = Hsum * (1.f / 17.f);
    finS[w][LI * 128 + 64 + lane] = zsum * (1.f / 17.f);
}

__global__ __launch_bounds__(256) void hse_fused_kernel(
    const float* __restrict__ kp, const float* __restrict__ sc,
    const float* __restrict__ W0, const float* __restrict__ b0,
    const float* __restrict__ W1, const float* __restrict__ b1,
    const float* __restrict__ W2, const float* __restrict__ b2,
    const float* __restrict__ We, const float* __restrict__ be,
    const float* __restrict__ Wp, const float* __restrict__ bp,
    float* __restrict__ out) {
    __shared__ float2 WW[64][64];
    __shared__ float beS[64];
    __shared__ float Praw[4][17][3];
    __shared__ float featS[4][64][8];
    __shared__ float finS[4][384];

    int tid = threadIdx.x;
    int w = tid >> 6;
    int lane = tid & 63;
    int sample = blockIdx.x * 4 + w;

    for (int i = tid; i < 4096; i += 256) {
        int t = i >> 6, d = i & 63;
        float wA = We[t * 128 + d];
        float wB = We[t * 128 + 64 + d];
        WW[d][t] = make_float2(wA - wB, wB);
    }
    if (tid < 64) beS[tid] = be[tid];
    if (lane < 17) {
        size_t base = (size_t)sample * 17 + lane;
        float2 xy = *(const float2*)(kp + base * 2);
        Praw[w][lane][0] = xy.x;
        Praw[w][lane][1] = xy.y;
        Praw[w][lane][2] = sc[base];
    }
    __syncthreads();

    float mnx = 1e30f, mxx = -1e30f, mny = 1e30f, mxy = -1e30f;
    for (int j = 0; j < 17; ++j) {
        float x = Praw[w][j][0], y = Praw[w][j][1];
        mnx = fminf(mnx, x); mxx = fmaxf(mxx, x);
        mny = fminf(mny, y); mxy = fmaxf(mxy, y);
    }
    float ix = 1.f / (mxx - mnx + 1e-6f);
    float iy = 1.f / (mxy - mny + 1e-6f);

    do_level_f<0, 5, 4>(w, lane, W0, b0, mnx, ix, mny, iy, Praw, featS, WW, beS, finS);
    do_level_f<1, 4, 9>(w, lane, W1, b1, mnx, ix, mny, iy, Praw, featS, WW, beS, finS);
    do_level_f<2, 4, 4>(w, lane, W2, b2, mnx, ix, mny, iy, Praw, featS, WW, beS, finS);
    __syncthreads();

    float acc0 = bp[lane];
    float acc1 = bp[64 + lane];
    const float* r0 = Wp + (size_t)lane * 384;
    const float* r1 = Wp + (size_t)(64 + lane) * 384;
    const float* fv = finS[w];
#pragma unroll 8
    for (int e = 0; e < 384; e += 4) {
        float4 wa = *(const float4*)(r0 + e);
        float4 wb = *(const float4*)(r1 + e);
        float4 ffv = *(const float4*)(fv + e);
        acc0 = fmaf(wa.x, ffv.x, acc0);
        acc0 = fmaf(wa.y, ffv.y, acc0);
        acc0 = fmaf(wa.z, ffv.z, acc0);
        acc0 = fmaf(wa.w, ffv.w, acc0);
        acc1 = fmaf(wb.x, ffv.x, acc1);
        acc1 = fmaf(wb.y, ffv.y, acc1);
        acc1 = fmaf(wb.z, ffv.z, acc1);
        acc1 = fmaf(wb.w, ffv.w, acc1);
    }
    out[(size_t)sample * 128 + lane] = acc0;
    out[(size_t)sample * 128 + 64 + lane] = acc1;
}

extern "C" void kernel_launch(void* const* d_in, const int* in_sizes, int n_in,
                              void* d_out, int out_size, void* d_ws, size_t ws_size,
                              hipStream_t stream) {
    const float* kp = (const float*)d_in[0];
    const float* sc = (const float*)d_in[1];
    const float* W0 = (const float*)d_in[2];
    const float* b0 = (const float*)d_in[3];
    const float* W1 = (const float*)d_in[4];
    const float* b1 = (const float*)d_in[5];
    const float* W2 = (const float*)d_in[6];
    const float* b2 = (const float*)d_in[7];
    const float* We = (const float*)d_in[8];
    const float* be = (const float*)d_in[9];
    const float* Wp = (const float*)d_in[10];
    const float* bp = (const float*)d_in[11];
    float* out = (float*)d_out;

    int N = in_sizes[0] / 34;  // keypoints N*17*2 -> 8192
    size_t finBytes = (size_t)N * 384 * sizeof(bf16);
    size_t need = finBytes + 49152 * sizeof(unsigned short);

    if (ws_size >= need) {
        bf16* fbuf = (bf16*)d_ws;
        unsigned short* wpB = (unsigned short*)((char*)d_ws + finBytes);
        hipLaunchKernelGGL(graph_kernel, dim3(N / 8), dim3(512), 0, stream,
                           kp, sc, W0, b0, W1, b1, W2, b2, We, be, Wp, wpB, fbuf);
        hipLaunchKernelGGL(out_mfma_kernel, dim3(N / 16), dim3(512), 0, stream,
                           fbuf, wpB, bp, out);
    } else {
        hipLaunchKernelGGL(hse_fused_kernel, dim3(N / 4), dim3(256), 0, stream,
                           kp, sc, W0, b0, W1, b1, W2, b2, We, be, Wp, bp, out);
    }
}

// Round 7
// 35.327 us; speedup vs baseline: 1.6455x; 1.6455x over previous
//
#include <hip/hip_runtime.h>
#include <hip/hip_bf16.h>

#define DEVINL __device__ __forceinline__

using bf16 = __hip_bfloat16;
typedef __attribute__((ext_vector_type(8))) short short8v;
typedef __attribute__((ext_vector_type(4))) float float4v;

DEVINL unsigned short f2bu(float x) { return __bfloat16_as_ushort(__float2bfloat16(x)); }

DEVINL short8v pk8(float4 a, float4 b) {
    union { unsigned short u[8]; short8v v; } r;
    r.u[0] = f2bu(a.x); r.u[1] = f2bu(a.y); r.u[2] = f2bu(a.z); r.u[3] = f2bu(a.w);
    r.u[4] = f2bu(b.x); r.u[5] = f2bu(b.y); r.u[6] = f2bu(b.z); r.u[7] = f2bu(b.w);
    return r.v;
}

// ===========================================================================
// K1: per-sample graph encoder with MFMA edge-GEMV.
// 512 thr = 8 waves = 8 samples/block, grid = N/8.
// Phase 1 (wave = sample, lane = channel d): normalize + level MLP + feat,
//   feat written TRANSPOSED to LDS as bf16 featT[joint][sample][d pad 80].
//   H-part of output written directly (validated r6 math).
// Phase 2 (wave = (t-tile, level-set)): a/c = feat @ {We1-We2, We2}^T + be
//   via mfma_f32_16x16x32_bf16: A row = sample (l&15, dup via &7),
//   k = (l>>4)*8+j; B col = t (l&15), from global fp32 We; C row =
//   (l>>4)*4+reg = sample, col = l&15 = t (m89-verified, validated r4/r5).
//   Z/max phase is lane-local on C fragments.
// Algebra (validated r2-r6): H_u = msum - m_u; msg = relu(a_j + c_k);
//   cross-level c==0; other-side a==be; OTH joints share max_k relu(be+c_k).
// ===========================================================================

template <int BASE, int CNT, int OTH, int LVL>
DEVINL void do_lvl_mfma(const unsigned short (*featT)[8][80],
                        int lane, int t, int sampBase,
                        const short8v bA[2], const short8v bC[2],
                        float4v binit, bf16* __restrict__ fout) {
    float4v zero = (float4v){0.f, 0.f, 0.f, 0.f};
    float4v aa[CNT], cc[CNT];
    int kq8 = (lane >> 4) * 8;
    int sl = lane & 7;
#pragma unroll
    for (int j = 0; j < CNT; ++j) {
        const unsigned short* base = &featT[BASE + j][sl][kq8];
        short8v a0 = *(const short8v*)base;
        short8v a1 = *(const short8v*)(base + 32);
        aa[j] = __builtin_amdgcn_mfma_f32_16x16x32_bf16(a0, bA[0], binit, 0, 0, 0);
        aa[j] = __builtin_amdgcn_mfma_f32_16x16x32_bf16(a1, bA[1], aa[j], 0, 0, 0);
        cc[j] = __builtin_amdgcn_mfma_f32_16x16x32_bf16(a0, bC[0], zero, 0, 0, 0);
        cc[j] = __builtin_amdgcn_mfma_f32_16x16x32_bf16(a1, bC[1], cc[j], 0, 0, 0);
    }
    float bet = binit[0];
    if ((lane >> 4) < 2) {   // rows 0..7 = the 8 real samples
#pragma unroll
        for (int r = 0; r < 4; ++r) {
            float a_[CNT], c_[CNT];
#pragma unroll
            for (int j = 0; j < CNT; ++j) { a_[j] = aa[j][r]; c_[j] = cc[j][r]; }
            float zs = 0.f;
#pragma unroll
            for (int j = 0; j < CNT; ++j) {
                float z = fmaxf(a_[j], 0.f);
#pragma unroll
                for (int k = 0; k < CNT; ++k) {
                    if (k != j) z = fmaxf(z, a_[j] + c_[k]);
                }
                zs += z;
            }
            float zo = 0.f;
#pragma unroll
            for (int k = 0; k < CNT; ++k) zo = fmaxf(zo, bet + c_[k]);
            zs += (float)OTH * zo;
            int s = sampBase + (lane >> 4) * 4 + r;
            fout[(size_t)s * 384 + LVL * 128 + 64 + t] = __float2bfloat16(zs * (1.f / 17.f));
        }
    }
}

__global__ __launch_bounds__(512) void graph_kernel(
    const float* __restrict__ kp, const float* __restrict__ sc,
    const float* __restrict__ W0, const float* __restrict__ b0,
    const float* __restrict__ W1, const float* __restrict__ b1,
    const float* __restrict__ W2, const float* __restrict__ b2,
    const float* __restrict__ We, const float* __restrict__ be,
    const float* __restrict__ Wp, unsigned short* __restrict__ wpB,
    bf16* __restrict__ fout) {
    __shared__ unsigned short featT[13][8][80];  // [joint][sample][d, pad 80]
    __shared__ float Praw[8][17][3];

    int tid = threadIdx.x;
    int w = tid >> 6;
    int lane = tid & 63;
    int sampBase = blockIdx.x * 8;
    int sample = sampBase + w;

    // ---- Wp -> bf16 conversion (first 12288 global threads) ----
    int gid = blockIdx.x * 512 + tid;
    if (gid < 12288) {
        float4 v = ((const float4*)Wp)[gid];
        union { unsigned short u[4]; uint2 d2; } pk;
        pk.u[0] = f2bu(v.x); pk.u[1] = f2bu(v.y);
        pk.u[2] = f2bu(v.z); pk.u[3] = f2bu(v.w);
        *(uint2*)&wpB[gid * 4] = pk.d2;
    }

    // ---- stage raw keypoints/scores: 8 samples x 17 joints ----
    for (int i = tid; i < 136; i += 512) {
        int s_l = i / 17, j = i - s_l * 17;
        size_t base = (size_t)(sampBase + s_l) * 17 + j;
        float2 xy = *(const float2*)(kp + base * 2);
        Praw[s_l][j][0] = xy.x;
        Praw[s_l][j][1] = xy.y;
        Praw[s_l][j][2] = sc[base];
    }
    __syncthreads();

    // =================== phase 1: wave = sample, lane = d ===================
    {
        // min/max via 32-wide shuffle butterfly (validated r3)
        int j5 = lane & 31;
        float xx = 0.f, yy = 0.f;
        if (j5 < 17) { xx = Praw[w][j5][0]; yy = Praw[w][j5][1]; }
        float mnx = (j5 < 17) ? xx : 1e30f, mxx = (j5 < 17) ? xx : -1e30f;
        float mny = (j5 < 17) ? yy : 1e30f, mxy = (j5 < 17) ? yy : -1e30f;
#pragma unroll
        for (int off = 16; off; off >>= 1) {
            mnx = fminf(mnx, __shfl_xor(mnx, off, 32));
            mxx = fmaxf(mxx, __shfl_xor(mxx, off, 32));
            mny = fminf(mny, __shfl_xor(mny, off, 32));
            mxy = fmaxf(mxy, __shfl_xor(mxy, off, 32));
        }
        float ix = 1.f / (mxx - mnx + 1e-6f);
        float iy = 1.f / (mxy - mny + 1e-6f);

        constexpr int JL[13]  = {0, 5, 6, 11, 12, 7, 8, 13, 14, 9, 10, 15, 16};
        constexpr int LEV[13] = {0, 0, 0, 0,  0,  1, 1, 1,  1,  2, 2,  2,  2};
        const float* Wls[3] = {W0, W1, W2};
        const float* bls[3] = {b0, b1, b2};
        float wx[3], wy[3], wsv[3], wb[3];
#pragma unroll
        for (int L = 0; L < 3; ++L) {
            wx[L] = Wls[L][lane * 3 + 0];
            wy[L] = Wls[L][lane * 3 + 1];
            wsv[L] = Wls[L][lane * 3 + 2];
            wb[L] = bls[L][lane];
        }

        float mj[13], sj[13];
        float msum[3] = {0.f, 0.f, 0.f};
#pragma unroll
        for (int jj = 0; jj < 13; ++jj) {
            int j = JL[jj];
            int L = LEV[jj];
            float px = (Praw[w][j][0] - mnx) * ix;
            float py = (Praw[w][j][1] - mny) * iy;
            float ps = Praw[w][j][2];
            float h = fmaxf(px * wx[L] + py * wy[L] + ps * wsv[L] + wb[L], 0.f);
            float m = h * ps;
            mj[jj] = m;
            sj[jj] = ps;
            msum[L] += m;
        }
        // feat -> LDS transposed (bf16); writes lane-contiguous: conflict-free
#pragma unroll
        for (int jj = 0; jj < 13; ++jj) {
            featT[jj][w][lane] = f2bu((msum[LEV[jj]] - mj[jj]) * sj[jj]);
        }
        // H-part outputs (lane = channel): Hsum_L = (CNT_L-1) * msum_L
        bf16* outv = fout + (size_t)sample * 384;
        outv[0 * 128 + lane] = __float2bfloat16(4.f * msum[0] * (1.f / 17.f));
        outv[1 * 128 + lane] = __float2bfloat16(3.f * msum[1] * (1.f / 17.f));
        outv[2 * 128 + lane] = __float2bfloat16(3.f * msum[2] * (1.f / 17.f));
    }
    __syncthreads();

    // ============ phase 2: wave = (t-tile, level-set), MFMA a/c ============
    {
        int tile = w >> 1;       // 0..3 -> t-groups of 16 (EH=64)
        int parity = w & 1;      // 0 -> level 0; 1 -> levels 1,2
        int t = tile * 16 + (lane & 15);
        int kq8 = (lane >> 4) * 8;

        // B-fragments from global fp32 We[t][0..127]: bA = We1-We2, bC = We2
        short8v bA[2], bC[2];
#pragma unroll
        for (int k = 0; k < 2; ++k) {
            int dbase = k * 32 + kq8;
            const float* r1 = We + t * 128 + dbase;
            const float* r2 = We + t * 128 + 64 + dbase;
            float4 x0 = *(const float4*)r1;
            float4 x1 = *(const float4*)(r1 + 4);
            float4 y0 = *(const float4*)r2;
            float4 y1 = *(const float4*)(r2 + 4);
            float4 d0 = make_float4(x0.x - y0.x, x0.y - y0.y, x0.z - y0.z, x0.w - y0.w);
            float4 d1 = make_float4(x1.x - y1.x, x1.y - y1.y, x1.z - y1.z, x1.w - y1.w);
            bA[k] = pk8(d0, d1);
            bC[k] = pk8(y0, y1);
        }
        float bet = be[t];
        float4v binit = (float4v){bet, bet, bet, bet};

        if (parity == 0) {
            do_lvl_mfma<0, 5, 4, 0>(featT, lane, t, sampBase, bA, bC, binit, fout);
        } else {
            do_lvl_mfma<5, 4, 9, 1>(featT, lane, t, sampBase, bA, bC, binit, fout);
            do_lvl_mfma<9, 4, 4, 2>(featT, lane, t, sampBase, bA, bC, binit, fout);
        }
    }
}

// ===========================================================================
// K2: out[8192][128] = fin(bf16)[8192][384] @ WpB^T + bp via MFMA 16x16x32.
// Unchanged from round 6. NO LDS, NO barriers. 512 blocks x 8 waves.
// ===========================================================================
__global__ __launch_bounds__(512) void out_mfma_kernel(
    const bf16* __restrict__ fin, const unsigned short* __restrict__ wpB,
    const float* __restrict__ bp, float* __restrict__ out) {
    int tid = threadIdx.x;
    int w = tid >> 6;
    int lane = tid & 63;
    int m0 = blockIdx.x * 16;
    int r16 = lane & 15;
    int kg = (lane >> 4) * 8;

    const short8v* aptr = (const short8v*)(fin + (size_t)(m0 + r16) * 384 + kg);
    const short8v* bptr = (const short8v*)(wpB + (size_t)(w * 16 + r16) * 384 + kg);

    float bv = bp[w * 16 + r16];
    float4v acc = (float4v){bv, bv, bv, bv};
#pragma unroll
    for (int kt = 0; kt < 12; ++kt) {
        short8v a = aptr[kt * 4];
        short8v b = bptr[kt * 4];
        acc = __builtin_amdgcn_mfma_f32_16x16x32_bf16(a, b, acc, 0, 0, 0);
    }

    int orow = m0 + (lane >> 4) * 4;
#pragma unroll
    for (int r = 0; r < 4; ++r) {
        out[(size_t)(orow + r) * 128 + w * 16 + r16] = acc[r];
    }
}

// ===========================================================================
// Fallback: validated round-2 fused kernel (used only if ws too small).
// ===========================================================================
template <int LI, int CNT, int OTH>
DEVINL void do_level_f(int w, int lane,
                       const float* __restrict__ Wl, const float* __restrict__ bl,
                       float mnx, float ix, float mny, float iy,
                       const float (*Praw)[17][3],
                       float (*featS)[64][8],
                       const float2 (*WW)[64],
                       const float* beS,
                       float (*finS)[384]) {
    constexpr int SUBJ[3][5] = {{0, 5, 6, 11, 12}, {7, 8, 13, 14, 16}, {9, 10, 15, 16, 16}};
    float w0 = Wl[lane * 3 + 0], w1 = Wl[lane * 3 + 1], w2 = Wl[lane * 3 + 2], bb = bl[lane];
    float mj[CNT], sj[CNT];
    float msum = 0.f;
#pragma unroll
    for (int jj = 0; jj < CNT; ++jj) {
        int j = SUBJ[LI][jj];
        float px = (Praw[w][j][0] - mnx) * ix;
        float py = (Praw[w][j][1] - mny) * iy;
        float ps = Praw[w][j][2];
        float h = fmaxf(px * w0 + py * w1 + ps * w2 + bb, 0.f);
        float m = h * ps;
        mj[jj] = m; sj[jj] = ps; msum += m;
    }
#pragma unroll
    for (int jj = 0; jj < CNT; ++jj) featS[w][lane][jj] = (msum - mj[jj]) * sj[jj];
    float Hsum = (float)(CNT - 1) * msum;
    __syncthreads();
    float a_[CNT], c_[CNT];
    float bet = beS[lane];
#pragma unroll
    for (int jj = 0; jj < CNT; ++jj) { a_[jj] = bet; c_[jj] = 0.f; }
#pragma unroll 4
    for (int d = 0; d < 64; ++d) {
        float2 wv = WW[d][lane];
        const float* fr = &featS[w][d][0];
        float4 f4 = *(const float4*)fr;
        float f[5];
        f[0] = f4.x; f[1] = f4.y; f[2] = f4.z; f[3] = f4.w; f[4] = 0.f;
        if constexpr (CNT > 4) f[4] = fr[4];
#pragma unroll
        for (int jj = 0; jj < CNT; ++jj) {
            a_[jj] = fmaf(wv.x, f[jj], a_[jj]);
            c_[jj] = fmaf(wv.y, f[jj], c_[jj]);
        }
    }
    __syncthreads();
    float zsum = 0.f;
#pragma unroll
    for (int jj = 0; jj < CNT; ++jj) {
        float z = fmaxf(a_[jj], 0.f);
#pragma unroll
        for (int kk = 0; kk < CNT; ++kk)
            if (kk != jj) z = fmaxf(z, a_[jj] + c_[kk]);
        zsum += z;
    }
    float zo = 0.f;
#pragma unroll
    for (int kk = 0; kk < CNT; ++kk) zo = fmaxf(zo, bet + c_[kk]);
    zsum += (float)OTH * zo;
    finS[w][LI * 128 + lane] = Hsum * (1.f / 17.f);
    finS[w][LI * 128 + 64 + lane] = zsum * (1.f / 17.f);
}

__global__ __launch_bounds__(256) void hse_fused_kernel(
    const float* __restrict__ kp, const float* __restrict__ sc,
    const float* __restrict__ W0, const float* __restrict__ b0,
    const float* __restrict__ W1, const float* __restrict__ b1,
    const float* __restrict__ W2, const float* __restrict__ b2,
    const float* __restrict__ We, const float* __restrict__ be,
    const float* __restrict__ Wp, const float* __restrict__ bp,
    float* __restrict__ out) {
    __shared__ float2 WW[64][64];
    __shared__ float beS[64];
    __shared__ float Praw[4][17][3];
    __shared__ float featS[4][64][8];
    __shared__ float finS[4][384];

    int tid = threadIdx.x;
    int w = tid >> 6;
    int lane = tid & 63;
    int sample = blockIdx.x * 4 + w;

    for (int i = tid; i < 4096; i += 256) {
        int t = i >> 6, d = i & 63;
        float wA = We[t * 128 + d];
        float wB = We[t * 128 + 64 + d];
        WW[d][t] = make_float2(wA - wB, wB);
    }
    if (tid < 64) beS[tid] = be[tid];
    if (lane < 17) {
        size_t base = (size_t)sample * 17 + lane;
        float2 xy = *(const float2*)(kp + base * 2);
        Praw[w][lane][0] = xy.x;
        Praw[w][lane][1] = xy.y;
        Praw[w][lane][2] = sc[base];
    }
    __syncthreads();

    float mnx = 1e30f, mxx = -1e30f, mny = 1e30f, mxy = -1e30f;
    for (int j = 0; j < 17; ++j) {
        float x = Praw[w][j][0], y = Praw[w][j][1];
        mnx = fminf(mnx, x); mxx = fmaxf(mxx, x);
        mny = fminf(mny, y); mxy = fmaxf(mxy, y);
    }
    float ix = 1.f / (mxx - mnx + 1e-6f);
    float iy = 1.f / (mxy - mny + 1e-6f);

    do_level_f<0, 5, 4>(w, lane, W0, b0, mnx, ix, mny, iy, Praw, featS, WW, beS, finS);
    do_level_f<1, 4, 9>(w, lane, W1, b1, mnx, ix, mny, iy, Praw, featS, WW, beS, finS);
    do_level_f<2, 4, 4>(w, lane, W2, b2, mnx, ix, mny, iy, Praw, featS, WW, beS, finS);
    __syncthreads();

    float acc0 = bp[lane];
    float acc1 = bp[64 + lane];
    const float* r0 = Wp + (size_t)lane * 384;
    const float* r1 = Wp + (size_t)(64 + lane) * 384;
    const float* fv = finS[w];
#pragma unroll 8
    for (int e = 0; e < 384; e += 4) {
        float4 wa = *(const float4*)(r0 + e);
        float4 wb = *(const float4*)(r1 + e);
        float4 ffv = *(const float4*)(fv + e);
        acc0 = fmaf(wa.x, ffv.x, acc0);
        acc0 = fmaf(wa.y, ffv.y, acc0);
        acc0 = fmaf(wa.z, ffv.z, acc0);
        acc0 = fmaf(wa.w, ffv.w, acc0);
        acc1 = fmaf(wb.x, ffv.x, acc1);
        acc1 = fmaf(wb.y, ffv.y, acc1);
        acc1 = fmaf(wb.z, ffv.z, acc1);
        acc1 = fmaf(wb.w, ffv.w, acc1);
    }
    out[(size_t)sample * 128 + lane] = acc0;
    out[(size_t)sample * 128 + 64 + lane] = acc1;
}

extern "C" void kernel_launch(void* const* d_in, const int* in_sizes, int n_in,
                              void* d_out, int out_size, void* d_ws, size_t ws_size,
                              hipStream_t stream) {
    const float* kp = (const float*)d_in[0];
    const float* sc = (const float*)d_in[1];
    const float* W0 = (const float*)d_in[2];
    const float* b0 = (const float*)d_in[3];
    const float* W1 = (const float*)d_in[4];
    const float* b1 = (const float*)d_in[5];
    const float* W2 = (const float*)d_in[6];
    const float* b2 = (const float*)d_in[7];
    const float* We = (const float*)d_in[8];
    const float* be = (const float*)d_in[9];
    const float* Wp = (const float*)d_in[10];
    const float* bp = (const float*)d_in[11];
    float* out = (float*)d_out;

    int N = in_sizes[0] / 34;  // keypoints N*17*2 -> 8192
    size_t finBytes = (size_t)N * 384 * sizeof(bf16);
    size_t need = finBytes + 49152 * sizeof(unsigned short);

    if (ws_size >= need) {
        bf16* fbuf = (bf16*)d_ws;
        unsigned short* wpB = (unsigned short*)((char*)d_ws + finBytes);
        hipLaunchKernelGGL(graph_kernel, dim3(N / 8), dim3(512), 0, stream,
                           kp, sc, W0, b0, W1, b1, W2, b2, We, be, Wp, wpB, fbuf);
        hipLaunchKernelGGL(out_mfma_kernel, dim3(N / 16), dim3(512), 0, stream,
                           fbuf, wpB, bp, out);
    } else {
        hipLaunchKernelGGL(hse_fused_kernel, dim3(N / 4), dim3(256), 0, stream,
                           kp, sc, W0, b0, W1, b1, W2, b2, We, be, Wp, bp, out);
    }
}

// Round 8
// 25.154 us; speedup vs baseline: 2.3109x; 1.4044x over previous
//
#include <hip/hip_runtime.h>
#include <hip/hip_bf16.h>

#define DEVINL __device__ __forceinline__

using bf16 = __hip_bfloat16;
typedef __attribute__((ext_vector_type(8))) short short8v;
typedef __attribute__((ext_vector_type(4))) float float4v;

DEVINL unsigned short f2bu(float x) { return __bfloat16_as_ushort(__float2bfloat16(x)); }

DEVINL short8v pk8(float4 a, float4 b) {
    union { unsigned short u[8]; short8v v; } r;
    r.u[0] = f2bu(a.x); r.u[1] = f2bu(a.y); r.u[2] = f2bu(a.z); r.u[3] = f2bu(a.w);
    r.u[4] = f2bu(b.x); r.u[5] = f2bu(b.y); r.u[6] = f2bu(b.z); r.u[7] = f2bu(b.w);
    return r.v;
}

// ===========================================================================
// Single fused kernel. 512 thr = 8 waves, 16 samples/block, grid = N/16.
//
// Phase 1 (wave = 2 samples, lane = channel d): normalize + level MLP + feat;
//   feat -> LDS bf16 featT[joint][sample][d] (stride 72: b128 reads hit the
//   8-lanes/bank even floor); H-part -> finS (validated r6 math).
// Phase 2 (wave = (t-tile, level-set)): a/c = feat @ {We1-We2, We2}^T + be
//   via mfma_f32_16x16x32_bf16, 16 REAL sample rows (no dup waste);
//   bias folded into MFMA C-in (validated r7). Z lane-local on C fragments,
//   all 64 lanes' rows real -> Z -> finS.
// Phase 3 (wave = 16-output n-tile): out = finS @ Wp^T + bp, A from LDS,
//   B built inline from fp32 Wp (L2-hot), bias via C-init (validated r6).
// Algebra (validated r2-r7): H_u = msum - m_u; msg = relu(a_j + c_k);
//   cross-level c==0; other-side a==be; OTH joints share max_k relu(be+c_k).
// MFMA layouts (m89-verified): A/B row/col = l&15, k = (l>>4)*8+j;
//   C row = (l>>4)*4+reg, col = l&15.
// ===========================================================================

template <int BASE, int CNT, int OTH, int LVL>
DEVINL void do_lvl_mfma(const unsigned short (*featT)[16][72],
                        int lane, int t,
                        const short8v bA[2], const short8v bC[2],
                        float4v binit, unsigned short (*finS)[392]) {
    float4v zero = (float4v){0.f, 0.f, 0.f, 0.f};
    float4v aa[CNT], cc[CNT];
    int kq8 = (lane >> 4) * 8;
    int sl = lane & 15;
#pragma unroll
    for (int j = 0; j < CNT; ++j) {
        const unsigned short* base = &featT[BASE + j][sl][kq8];
        short8v a0 = *(const short8v*)base;
        short8v a1 = *(const short8v*)(base + 32);
        aa[j] = __builtin_amdgcn_mfma_f32_16x16x32_bf16(a0, bA[0], binit, 0, 0, 0);
        aa[j] = __builtin_amdgcn_mfma_f32_16x16x32_bf16(a1, bA[1], aa[j], 0, 0, 0);
        cc[j] = __builtin_amdgcn_mfma_f32_16x16x32_bf16(a0, bC[0], zero, 0, 0, 0);
        cc[j] = __builtin_amdgcn_mfma_f32_16x16x32_bf16(a1, bC[1], cc[j], 0, 0, 0);
    }
    float bet = binit[0];
#pragma unroll
    for (int r = 0; r < 4; ++r) {
        float a_[CNT], c_[CNT];
#pragma unroll
        for (int j = 0; j < CNT; ++j) { a_[j] = aa[j][r]; c_[j] = cc[j][r]; }
        float zs = 0.f;
#pragma unroll
        for (int j = 0; j < CNT; ++j) {
            float z = fmaxf(a_[j], 0.f);
#pragma unroll
            for (int k = 0; k < CNT; ++k) {
                if (k != j) z = fmaxf(z, a_[j] + c_[k]);
            }
            zs += z;
        }
        float zo = 0.f;
#pragma unroll
        for (int k = 0; k < CNT; ++k) zo = fmaxf(zo, bet + c_[k]);
        zs += (float)OTH * zo;
        int s = (lane >> 4) * 4 + r;   // C row = sample, all 16 real
        finS[s][LVL * 128 + 64 + t] = f2bu(zs * (1.f / 17.f));
    }
}

__global__ __launch_bounds__(512) void hse_one_kernel(
    const float* __restrict__ kp, const float* __restrict__ sc,
    const float* __restrict__ W0, const float* __restrict__ b0,
    const float* __restrict__ W1, const float* __restrict__ b1,
    const float* __restrict__ W2, const float* __restrict__ b2,
    const float* __restrict__ We, const float* __restrict__ be,
    const float* __restrict__ Wp, const float* __restrict__ bp,
    float* __restrict__ out) {
    __shared__ float Praw[16][17][3];            // 3.3 KB
    __shared__ unsigned short featT[13][16][72]; // 30.0 KB [joint][sample][d]
    __shared__ unsigned short finS[16][392];     // 12.5 KB [sample][feature]

    int tid = threadIdx.x;
    int w = tid >> 6;
    int lane = tid & 63;
    int sampBase = blockIdx.x * 16;

    // ---- stage raw keypoints/scores: 16 samples x 17 joints ----
    if (tid < 272) {
        int s = tid / 17, j = tid - s * 17;
        size_t base = (size_t)(sampBase + s) * 17 + j;
        float2 xy = *(const float2*)(kp + base * 2);
        Praw[s][j][0] = xy.x;
        Praw[s][j][1] = xy.y;
        Praw[s][j][2] = sc[base];
    }
    __syncthreads();

    // =============== phase 1: wave = samples {2w, 2w+1}, lane = d ==========
    {
        constexpr int JL[13]  = {0, 5, 6, 11, 12, 7, 8, 13, 14, 9, 10, 15, 16};
        constexpr int LEV[13] = {0, 0, 0, 0,  0,  1, 1, 1,  1,  2, 2,  2,  2};
        const float* Wls[3] = {W0, W1, W2};
        const float* bls[3] = {b0, b1, b2};
        float wx[3], wy[3], wsv[3], wb[3];
#pragma unroll
        for (int L = 0; L < 3; ++L) {
            wx[L] = Wls[L][lane * 3 + 0];
            wy[L] = Wls[L][lane * 3 + 1];
            wsv[L] = Wls[L][lane * 3 + 2];
            wb[L] = bls[L][lane];
        }

#pragma unroll
        for (int half = 0; half < 2; ++half) {
            int s = 2 * w + half;
            // min/max via 32-wide shuffle butterfly (validated r3)
            int j5 = lane & 31;
            float xx = 0.f, yy = 0.f;
            if (j5 < 17) { xx = Praw[s][j5][0]; yy = Praw[s][j5][1]; }
            float mnx = (j5 < 17) ? xx : 1e30f, mxx = (j5 < 17) ? xx : -1e30f;
            float mny = (j5 < 17) ? yy : 1e30f, mxy = (j5 < 17) ? yy : -1e30f;
#pragma unroll
            for (int off = 16; off; off >>= 1) {
                mnx = fminf(mnx, __shfl_xor(mnx, off, 32));
                mxx = fmaxf(mxx, __shfl_xor(mxx, off, 32));
                mny = fminf(mny, __shfl_xor(mny, off, 32));
                mxy = fmaxf(mxy, __shfl_xor(mxy, off, 32));
            }
            float ix = 1.f / (mxx - mnx + 1e-6f);
            float iy = 1.f / (mxy - mny + 1e-6f);

            float mj[13], sj[13];
            float msum[3] = {0.f, 0.f, 0.f};
#pragma unroll
            for (int jj = 0; jj < 13; ++jj) {
                int j = JL[jj];
                int L = LEV[jj];
                float px = (Praw[s][j][0] - mnx) * ix;
                float py = (Praw[s][j][1] - mny) * iy;
                float ps = Praw[s][j][2];
                float h = fmaxf(px * wx[L] + py * wy[L] + ps * wsv[L] + wb[L], 0.f);
                float m = h * ps;
                mj[jj] = m;
                sj[jj] = ps;
                msum[L] += m;
            }
#pragma unroll
            for (int jj = 0; jj < 13; ++jj) {
                featT[jj][s][lane] = f2bu((msum[LEV[jj]] - mj[jj]) * sj[jj]);
            }
            // H-part: Hsum_L = (CNT_L - 1) * msum_L (validated r6)
            finS[s][0 * 128 + lane] = f2bu(4.f * msum[0] * (1.f / 17.f));
            finS[s][1 * 128 + lane] = f2bu(3.f * msum[1] * (1.f / 17.f));
            finS[s][2 * 128 + lane] = f2bu(3.f * msum[2] * (1.f / 17.f));
        }
    }
    __syncthreads();

    // ============ phase 2: wave = (t-tile, level-set), MFMA a/c ============
    {
        int tile = w >> 1;       // 0..3 -> t-groups of 16 (EH=64)
        int parity = w & 1;      // 0 -> level 0; 1 -> levels 1,2
        int t = tile * 16 + (lane & 15);
        int kq8 = (lane >> 4) * 8;

        // B-fragments from global fp32 We[t][0..127]: bA = We1-We2, bC = We2
        short8v bA[2], bC[2];
#pragma unroll
        for (int k = 0; k < 2; ++k) {
            int dbase = k * 32 + kq8;
            const float* r1 = We + t * 128 + dbase;
            const float* r2 = We + t * 128 + 64 + dbase;
            float4 x0 = *(const float4*)r1;
            float4 x1 = *(const float4*)(r1 + 4);
            float4 y0 = *(const float4*)r2;
            float4 y1 = *(const float4*)(r2 + 4);
            float4 d0 = make_float4(x0.x - y0.x, x0.y - y0.y, x0.z - y0.z, x0.w - y0.w);
            float4 d1 = make_float4(x1.x - y1.x, x1.y - y1.y, x1.z - y1.z, x1.w - y1.w);
            bA[k] = pk8(d0, d1);
            bC[k] = pk8(y0, y1);
        }
        float bet = be[t];
        float4v binit = (float4v){bet, bet, bet, bet};

        if (parity == 0) {
            do_lvl_mfma<0, 5, 4, 0>(featT, lane, t, bA, bC, binit, finS);
        } else {
            do_lvl_mfma<5, 4, 9, 1>(featT, lane, t, bA, bC, binit, finS);
            do_lvl_mfma<9, 4, 4, 2>(featT, lane, t, bA, bC, binit, finS);
        }
    }
    __syncthreads();

    // ====== phase 3: wave = n-tile w; out = finS @ Wp^T + bp (MFMA) ========
    {
        int o = w * 16 + (lane & 15);
        int kq8 = (lane >> 4) * 8;
        const float* wrow = Wp + (size_t)o * 384;
        float bv = bp[o];
        float4v acc = (float4v){bv, bv, bv, bv};
#pragma unroll
        for (int kt = 0; kt < 12; ++kt) {
            short8v a = *(const short8v*)&finS[lane & 15][kt * 32 + kq8];
            const float* wp8 = wrow + kt * 32 + kq8;
            float4 x0 = *(const float4*)wp8;
            float4 x1 = *(const float4*)(wp8 + 4);
            short8v b = pk8(x0, x1);
            acc = __builtin_amdgcn_mfma_f32_16x16x32_bf16(a, b, acc, 0, 0, 0);
        }
        int srow = (lane >> 4) * 4;
#pragma unroll
        for (int r = 0; r < 4; ++r) {
            out[(size_t)(sampBase + srow + r) * 128 + o] = acc[r];
        }
    }
}

extern "C" void kernel_launch(void* const* d_in, const int* in_sizes, int n_in,
                              void* d_out, int out_size, void* d_ws, size_t ws_size,
                              hipStream_t stream) {
    const float* kp = (const float*)d_in[0];
    const float* sc = (const float*)d_in[1];
    const float* W0 = (const float*)d_in[2];
    const float* b0 = (const float*)d_in[3];
    const float* W1 = (const float*)d_in[4];
    const float* b1 = (const float*)d_in[5];
    const float* W2 = (const float*)d_in[6];
    const float* b2 = (const float*)d_in[7];
    const float* We = (const float*)d_in[8];
    const float* be = (const float*)d_in[9];
    const float* Wp = (const float*)d_in[10];
    const float* bp = (const float*)d_in[11];
    float* out = (float*)d_out;

    int N = in_sizes[0] / 34;  // keypoints N*17*2 -> 8192
    hipLaunchKernelGGL(hse_one_kernel, dim3(N / 16), dim3(512), 0, stream,
                       kp, sc, W0, b0, W1, b1, W2, b2, We, be, Wp, bp, out);
}